// Round 6
// baseline (522.021 us; speedup 1.0000x reference)
//
#include <hip/hip_runtime.h>
#include <hip/hip_bf16.h>
#include <cstdint>

typedef unsigned short u16;
typedef __attribute__((ext_vector_type(8))) short short8;
typedef __attribute__((ext_vector_type(4))) float f32x4;
typedef __attribute__((ext_vector_type(4))) unsigned short u16x4;
typedef __attribute__((ext_vector_type(4))) unsigned int u32x4;

#define NSEQ 2048
#define DMODEL 1024
#define NH 8
#define HD 128
#define KDIM 1024
// 1/sqrt(128) * log2(e): attention computed in exp2 domain
#define QSCALE (0.08838834764831845f * 1.4426950408889634f)

__device__ __forceinline__ u16 f2b(float f) {
  __hip_bfloat16 h = __float2bfloat16(f);
  union { __hip_bfloat16 h; u16 u; } cv; cv.h = h; return cv.u;
}
__device__ __forceinline__ float b2f(u16 u) {
  union { float f; unsigned v; } c; c.v = ((unsigned)u) << 16; return c.f;
}
__device__ __forceinline__ f32x4 zero4() { f32x4 z = {0.f, 0.f, 0.f, 0.f}; return z; }

// async global->LDS, 16B per lane. LDS dest is wave-uniform base + lane*16.
__device__ __forceinline__ void gload_lds16(const u16* g, u16* l) {
  __builtin_amdgcn_global_load_lds(
      (__attribute__((address_space(1))) void*)g,
      (__attribute__((address_space(3))) void*)l, 16, 0, 0);
}

// K-row permutation: sK physical row r holds K logical row LK(r) of the tile.
// Swapped-QK (mfma(K,Q)) output then lands IN-REGISTER in the exact PV
// A-fragment layout (kv = 8*quad + 4*n + rr). Valid for 32-row tiles too.
__device__ __forceinline__ int LK(int r) {
  return (r & 0x23) | ((r & 0x0C) << 1) | ((r & 0x10) >> 2);
}

// ---------------- fp32 -> bf16 convert (X) ----------------
__global__ void cvt_f32_bf16(const float* __restrict__ in, u16* __restrict__ out) {
  const size_t i = ((size_t)blockIdx.x * 256 + threadIdx.x) * 8;
  f32x4 a = *(const f32x4*)&in[i];
  f32x4 b = *(const f32x4*)&in[i + 4];
  short8 o;
#pragma unroll
  for (int j = 0; j < 4; ++j) { o[j] = (short)f2b(a[j]); o[4 + j] = (short)f2b(b[j]); }
  *(short8*)&out[i] = o;
}

// ------------- weight transpose + fp32->bf16 convert: [R][C] -> [C][R] -------------
__global__ void transpose_k(const float* __restrict__ in, u16* __restrict__ out,
                            int R, int C) {
  __shared__ u16 tile[32][33];
  const int tx = threadIdx.x, ty = threadIdx.y;
  const int c = blockIdx.x * 32 + tx;
  const int r0 = blockIdx.y * 32;
  for (int i = ty; i < 32; i += 8) tile[i][tx] = f2b(in[(size_t)(r0 + i) * C + c]);
  __syncthreads();
  const int oc = r0 + tx;
  const int c0 = blockIdx.x * 32;
  for (int i = ty; i < 32; i += 8) out[(size_t)(c0 + i) * R + oc] = tile[tx][i];
}

// ---------------- 128x128 GEMM, A[M][K] @ Bt[N][K]^T, K=1024, all bf16 in ----
// 1-D grid + bijective XCD swizzle (T1): consecutive swizzled ids share the
// A row-panel within one XCD's L2. NT = N/128 tiles per row.
template <int MODE>
__global__ __launch_bounds__(256, 3) void gemm128(
    const u16* __restrict__ A, const u16* __restrict__ Bt,
    const float* __restrict__ bias, u16* __restrict__ o0,
    u16* __restrict__ o1, u16* __restrict__ o2, float* __restrict__ of) {
  __shared__ __align__(16) u16 sA[128 * 64];
  __shared__ __align__(16) u16 sB[128 * 64];

  const int tid = threadIdx.x;
  const int lane = tid & 63;
  const int w = tid >> 6;
  const int quad = lane >> 4, ln = lane & 15;

  const int NT = (MODE == 0) ? 24 : 8;     // N/128
  const int nwg = gridDim.x, cpx = nwg >> 3;
  const int id = blockIdx.x;
  const int swz = (id & 7) * cpx + (id >> 3);   // bijective: nwg % 8 == 0
  const int m0 = (swz / NT) * 128, n0 = (swz % NT) * 128;

  const int wm = (w >> 1) * 64, wn = (w & 1) * 64;

  f32x4 acc[4][4];
#pragma unroll
  for (int i = 0; i < 4; ++i)
#pragma unroll
    for (int j = 0; j < 4; ++j) acc[i][j] = zero4();

  const int cbase = w * 4;
  for (int kb = 0; kb < KDIM / 64; ++kb) {
    __syncthreads();   // prev iter's LDS reads done
    const int k0 = kb * 64;
#pragma unroll
    for (int i = 0; i < 4; ++i) {
      int c = (cbase + i) * 64 + lane;
      int r = c >> 3, s = c & 7;
      gload_lds16(A + (size_t)(m0 + r) * KDIM + k0 + s * 8, &sA[(cbase + i) * 512]);
      gload_lds16(Bt + (size_t)(n0 + r) * KDIM + k0 + s * 8, &sB[(cbase + i) * 512]);
    }
    __syncthreads();   // drains vmcnt (global_load_lds) per barrier semantics
#pragma unroll
    for (int ks = 0; ks < 2; ++ks) {
      short8 af[4], bf[4];
      const int kc = ks * 4 + quad;    // k-chunk 0..7
#pragma unroll
      for (int t = 0; t < 4; ++t) {
        af[t] = *(const short8*)&sA[(wm + t * 16 + ln) * 64 + kc * 8];
        bf[t] = *(const short8*)&sB[(wn + t * 16 + ln) * 64 + kc * 8];
      }
#pragma unroll
      for (int mt = 0; mt < 4; ++mt)
#pragma unroll
        for (int nt = 0; nt < 4; ++nt)
          acc[mt][nt] = __builtin_amdgcn_mfma_f32_16x16x32_bf16(
              af[mt], bf[nt], acc[mt][nt], 0, 0, 0);
    }
  }

  if (MODE == 0) {
    const int which = n0 >> 10;           // 0=Q 1=K 2=V (tile never crosses)
    const int h = (n0 & 1023) >> 7;       // head, block-uniform
#pragma unroll
    for (int mt = 0; mt < 4; ++mt) {
      const int rbase = m0 + wm + mt * 16 + quad * 4;  // 4 consecutive rows
      const int b = rbase >> 11;
      const int n = rbase & 2047;
#pragma unroll
      for (int nt = 0; nt < 4; ++nt) {
        const int dcol = wn + nt * 16 + ln;            // 0..127
        const float bv = bias[n0 + dcol];
        if (which == 0) {
          u16* p = o0 + ((size_t)(b * NH + h) * NSEQ + n) * HD + dcol;
#pragma unroll
          for (int rr = 0; rr < 4; ++rr)
            p[(size_t)rr * HD] = f2b((acc[mt][nt][rr] + bv) * QSCALE);
        } else if (which == 1) {
          u16* p = o1 + ((size_t)(b * NH + h) * NSEQ + n) * HD + dcol;
#pragma unroll
          for (int rr = 0; rr < 4; ++rr)
            p[(size_t)rr * HD] = f2b(acc[mt][nt][rr] + bv);
        } else {
          u16x4 pk;
#pragma unroll
          for (int rr = 0; rr < 4; ++rr) pk[rr] = f2b(acc[mt][nt][rr] + bv);
          *(u16x4*)&o2[((size_t)(b * NH + h) * HD + dcol) * NSEQ + n] = pk;
        }
      }
    }
  } else {
#pragma unroll
    for (int mt = 0; mt < 4; ++mt) {
      const int rbase = m0 + wm + mt * 16 + quad * 4;
#pragma unroll
      for (int nt = 0; nt < 4; ++nt) {
        const int col = n0 + wn + nt * 16 + ln;
        const float bv = bias[col];
#pragma unroll
        for (int rr = 0; rr < 4; ++rr)
          of[(size_t)(rbase + rr) * DMODEL + col] = acc[mt][nt][rr] + bv;
      }
    }
  }
}

// ------------- flash attention, SPLIT-K over kv: grid (N/128, B*H, 2) -------------
// R6: occupancy was the wall (2 waves/SIMD is structural: 2048 waves total).
// Split kv into 2 halves -> 1024 blocks; KVBLK=32 -> 32KB LDS/block ->
// 4 blocks/CU = 4 waves/SIMD. exp2-unnormalized softmax has no running max, so
// partials simply ADD: each split writes raw O (bf16) + per-row l (f32);
// a tiny combine kernel merges. All R5 machinery kept (LK permute -> P
// in-register, XOR swizzles, dbuf gload_lds staging, SM pipelined behind QK).
__global__ __launch_bounds__(256, 4) void attn_fused(
    const u16* __restrict__ Q, const u16* __restrict__ K,
    const u16* __restrict__ Vt, u16* __restrict__ OP0,
    u16* __restrict__ OP1, float* __restrict__ Lp) {
  __shared__ __align__(16) u16 sK[2][32 * 128];   // [kv_phys(LK-permuted)][d]
  __shared__ __align__(16) u16 sV[2][128 * 32];   // [d][kv]

  const int tid = threadIdx.x;
  const int w = tid >> 6, lane = tid & 63;
  const int quad = lane >> 4, ln = lane & 15;
  const int bh = blockIdx.y;
  const int q0 = blockIdx.x * 128;
  const int s = blockIdx.z;
  const int kv0 = s * (NSEQ / 2);
  const int kvend = kv0 + NSEQ / 2;

  const u16* Qb = Q + ((size_t)bh * NSEQ + q0) * HD;
  const u16* Kb = K + (size_t)bh * NSEQ * HD;
  const u16* Vb = Vt + (size_t)bh * HD * NSEQ;

  // staging source offsets (u16 units): LDS dest linear, source carries the
  // LK row-permute (K) and the slot^row XOR swizzle (K and V).
  // K tile: 32 rows x 16 slots (512 chunks); V tile: 128 rows x 4 slots.
  int gk_off[2], gv_off[2];
#pragma unroll
  for (int j = 0; j < 2; ++j) {
    const int c = j * 256 + w * 64 + lane;      // 16B-chunk id 0..511
    const int rk = c >> 4, sk_ = c & 15;
    gk_off[j] = LK(rk) * HD + (sk_ ^ (rk & 7)) * 8;
    const int rv = c >> 2, sv_ = c & 3;
    gv_off[j] = rv * NSEQ + (sv_ ^ (rv & 3)) * 8;
  }

  // loop-invariant LDS read offsets (u16 units)
  int kbase[2], kslot[4], vfo[8];
#pragma unroll
  for (int n = 0; n < 2; ++n) kbase[n] = (n * 16 + ln) * 128;
#pragma unroll
  for (int ks = 0; ks < 4; ++ks)
    kslot[ks] = (((ks << 2) | quad) ^ (ln & 7)) * 8;
#pragma unroll
  for (int dt = 0; dt < 8; ++dt)
    vfo[dt] = (dt * 16 + ln) * 32 + ((quad ^ (ln & 3)) * 8);

  // Q fragments (B-operand layout) straight from global (one-time)
  short8 qf[2][4];
#pragma unroll
  for (int mt = 0; mt < 2; ++mt)
#pragma unroll
    for (int ks = 0; ks < 4; ++ks)
      qf[mt][ks] = *(const short8*)&Qb[(size_t)(w * 32 + mt * 16 + ln) * HD +
                                       ks * 32 + quad * 8];

  f32x4 o[2][8];
#pragma unroll
  for (int mt = 0; mt < 2; ++mt)
#pragma unroll
    for (int dt = 0; dt < 8; ++dt) o[mt][dt] = zero4();
  float l_part[2] = {0.f, 0.f};

  // stage tile 0 into buffer 0
#pragma unroll
  for (int j = 0; j < 2; ++j) {
    gload_lds16(Kb + (size_t)kv0 * HD + gk_off[j], &sK[0][(j * 256 + w * 64) * 8]);
    gload_lds16(Vb + kv0 + gv_off[j], &sV[0][(j * 256 + w * 64) * 8]);
  }

  union PU { u32x4 u; short8 s; };

#pragma unroll 1
  for (int it = 0; it < (NSEQ / 2) / 64; ++it) {
#pragma unroll
    for (int c2 = 0; c2 < 2; ++c2) {
      const int kv = kv0 + (it * 2 + c2) * 32;
      __syncthreads();  // drains vmcnt: buf[c2] ready; buf[c2^1] reads done

      const int kvn = kv + 32;
      if (kvn < kvend) {   // prefetch next tile into the other buffer
#pragma unroll
        for (int j = 0; j < 2; ++j) {
          gload_lds16(Kb + (size_t)kvn * HD + gk_off[j],
                      &sK[c2 ^ 1][(j * 256 + w * 64) * 8]);
          gload_lds16(Vb + kvn + gv_off[j], &sV[c2 ^ 1][(j * 256 + w * 64) * 8]);
        }
      }
      const u16* skr = &sK[c2][0];
      const u16* svr = &sV[c2][0];

      __builtin_amdgcn_s_setprio(1);

      f32x4 sacc[2][2];   // [n][mt]
      PU ph[2];           // [mt] packed P (PV A-fragment, kv = 8quad+4n+rr)
      short8 vf[8];

      // SM chunk for completed n-tile m: exp2 + l-sum + cheap bf16 pair-pack
      auto SM = [&](int m) {
#pragma unroll
        for (int mt = 0; mt < 2; ++mt) {
          float e0 = exp2f(sacc[m][mt][0]);
          float e1 = exp2f(sacc[m][mt][1]);
          float e2 = exp2f(sacc[m][mt][2]);
          float e3 = exp2f(sacc[m][mt][3]);
          l_part[mt] += (e0 + e1) + (e2 + e3);
          unsigned a0 = __float_as_uint(e0) + 0x8000u;
          unsigned a1 = __float_as_uint(e1) + 0x8000u;
          unsigned a2 = __float_as_uint(e2) + 0x8000u;
          unsigned a3 = __float_as_uint(e3) + 0x8000u;
          ph[mt].u[m * 2 + 0] = __builtin_amdgcn_perm(a1, a0, 0x07060302);
          ph[mt].u[m * 2 + 1] = __builtin_amdgcn_perm(a3, a2, 0x07060302);
        }
      };

      // QK n=0
#pragma unroll
      for (int mt = 0; mt < 2; ++mt) sacc[0][mt] = zero4();
#pragma unroll
      for (int ks = 0; ks < 4; ++ks) {
        short8 kf = *(const short8*)&skr[kbase[0] + kslot[ks]];
        sacc[0][0] = __builtin_amdgcn_mfma_f32_16x16x32_bf16(
            kf, qf[0][ks], sacc[0][0], 0, 0, 0);
        sacc[0][1] = __builtin_amdgcn_mfma_f32_16x16x32_bf16(
            kf, qf[1][ks], sacc[0][1], 0, 0, 0);
      }
      // vf 0..3 reads issue under the QK MFMAs (LDS pipe || matrix pipe)
#pragma unroll
      for (int dt = 0; dt < 4; ++dt)
        vf[dt] = *(const short8*)&svr[vfo[dt]];
      // QK n=1
#pragma unroll
      for (int mt = 0; mt < 2; ++mt) sacc[1][mt] = zero4();
#pragma unroll
      for (int ks = 0; ks < 4; ++ks) {
        short8 kf = *(const short8*)&skr[kbase[1] + kslot[ks]];
        sacc[1][0] = __builtin_amdgcn_mfma_f32_16x16x32_bf16(
            kf, qf[0][ks], sacc[1][0], 0, 0, 0);
        sacc[1][1] = __builtin_amdgcn_mfma_f32_16x16x32_bf16(
            kf, qf[1][ks], sacc[1][1], 0, 0, 0);
      }
      SM(0);
#pragma unroll
      for (int dt = 4; dt < 8; ++dt)
        vf[dt] = *(const short8*)&svr[vfo[dt]];
      SM(1);

      // PV: O += P @ V (16 MFMA)
#pragma unroll
      for (int dt = 0; dt < 8; ++dt) {
        o[0][dt] = __builtin_amdgcn_mfma_f32_16x16x32_bf16(
            ph[0].s, vf[dt], o[0][dt], 0, 0, 0);
        o[1][dt] = __builtin_amdgcn_mfma_f32_16x16x32_bf16(
            ph[1].s, vf[dt], o[1][dt], 0, 0, 0);
      }
      __builtin_amdgcn_s_setprio(0);
    }
  }

  // epilogue: write UNNORMALIZED partial O (bf16) + per-row l (f32).
  u16* OP = (s == 0) ? OP0 : OP1;
  const int b = bh >> 3, h = bh & 7;
#pragma unroll
  for (int mt = 0; mt < 2; ++mt) {
    float v = l_part[mt];
    v += __shfl_xor(v, 16, 64);
    v += __shfl_xor(v, 32, 64);
    if (quad == 0)
      Lp[(size_t)s * 65536 + bh * NSEQ + q0 + w * 32 + mt * 16 + ln] = v;
    const int rbase = q0 + w * 32 + mt * 16 + quad * 4;
#pragma unroll
    for (int dt = 0; dt < 8; ++dt) {
      const int d = dt * 16 + ln;
#pragma unroll
      for (int rr = 0; rr < 4; ++rr)
        OP[((size_t)b * NSEQ + rbase + rr) * DMODEL + h * HD + d] =
            f2b(o[mt][dt][rr]);
    }
  }
}

// ------------- combine split-K partials: AO = (P0 + P1) / (l0 + l1) -------------
__global__ void combine_attn(const u16* __restrict__ P0, u16* AO,
                             const float* __restrict__ Lp) {
  const size_t i0 = ((size_t)blockIdx.x * 256 + threadIdx.x) * 8;
  const int n = (int)((i0 >> 10) & 2047);
  const int b = (int)(i0 >> 21);
  const int h = (int)((i0 >> 7) & 7);
  const int bh = b * NH + h;
  const float l = Lp[bh * NSEQ + n] + Lp[65536 + bh * NSEQ + n];
  const float inv = 1.0f / l;
  short8 p0 = *(const short8*)&P0[i0];
  short8 p1 = *(const short8*)&AO[i0];
  short8 r;
#pragma unroll
  for (int j = 0; j < 8; ++j)
    r[j] = (short)f2b((b2f((u16)p0[j]) + b2f((u16)p1[j])) * inv);
  *(short8*)&AO[i0] = r;
}

extern "C" void kernel_launch(void* const* d_in, const int* in_sizes, int n_in,
                              void* d_out, int out_size, void* d_ws, size_t ws_size,
                              hipStream_t stream) {
  // ALL tensors are FP32 per the reference (jnp.float32 everywhere).
  const float* X = (const float*)d_in[0];      // [4,2048,1024]
  const float* Wqkv = (const float*)d_in[1];   // [1024,3072]
  const float* bqkv = (const float*)d_in[2];   // [3072]
  const float* Wproj = (const float*)d_in[3];  // [1024,1024]
  const float* bproj = (const float*)d_in[4];  // [1024]
  float* out = (float*)d_out;                  // [4,2048,1024] fp32

  // workspace layout (u16 elements): ~92.3 MB total (unchanged).
  // Split-K reuse: Opart0 -> Xb (dead after gemm0), Opart1 -> AO (combined
  // in-place), Lp -> WqkvT region (dead after gemm0).
  const size_t NEED_BYTES =
      2ull * (8388608 /*Xb*/ + 3072 * 1024 + 1024 * 1024 + 3 * 8388608 + 8388608);
  if (ws_size < NEED_BYTES) return;  // signature: absmax == 0.2676 -> ws too small

  u16* ws = (u16*)d_ws;
  u16* Xb = ws;                            // [8192][1024] bf16
  u16* WqkvT = Xb + 8388608;               // [3072][1024] bf16
  u16* WprojT = WqkvT + 3072 * 1024;       // [1024][1024] bf16
  u16* Qb = WprojT + 1024 * 1024;          // [B,H,N,Hd] bf16 (pre-scaled, exp2 dom)
  u16* Kb = Qb + 8388608;                  // [B,H,N,Hd] bf16
  u16* Vtb = Kb + 8388608;                 // [B,H,Hd,N] bf16
  u16* AO = Vtb + 8388608;                 // [B,N,D]   bf16

  cvt_f32_bf16<<<8388608 / (256 * 8), 256, 0, stream>>>(X, Xb);
  transpose_k<<<dim3(3072 / 32, 1024 / 32), dim3(32, 8), 0, stream>>>(Wqkv, WqkvT, 1024, 3072);
  transpose_k<<<dim3(1024 / 32, 1024 / 32), dim3(32, 8), 0, stream>>>(Wproj, WprojT, 1024, 1024);
  gemm128<0><<<1536, 256, 0, stream>>>(Xb, WqkvT, bqkv, Qb, Kb, Vtb, nullptr);
  attn_fused<<<dim3(2048 / 128, 32, 2), 256, 0, stream>>>(
      Qb, Kb, Vtb, /*OP0=*/Xb, /*OP1=*/AO, /*Lp=*/(float*)WqkvT);
  combine_attn<<<8388608 / (256 * 8), 256, 0, stream>>>(Xb, AO, (const float*)WqkvT);
  gemm128<1><<<512, 256, 0, stream>>>(AO, WprojT, bproj, nullptr, nullptr, nullptr, out);
}

// Round 7
// 269.824 us; speedup vs baseline: 1.9347x; 1.9347x over previous
//
#include <hip/hip_runtime.h>
#include <hip/hip_bf16.h>
#include <cstdint>

typedef unsigned short u16;
typedef __attribute__((ext_vector_type(8))) short short8;
typedef __attribute__((ext_vector_type(4))) float f32x4;
typedef __attribute__((ext_vector_type(4))) unsigned short u16x4;
typedef __attribute__((ext_vector_type(4))) unsigned int u32x4;

#define NSEQ 2048
#define DMODEL 1024
#define NH 8
#define HD 128
#define KDIM 1024
// 1/sqrt(128) * log2(e): attention computed in exp2 domain
#define QSCALE (0.08838834764831845f * 1.4426950408889634f)

__device__ __forceinline__ u16 f2b(float f) {
  __hip_bfloat16 h = __float2bfloat16(f);
  union { __hip_bfloat16 h; u16 u; } cv; cv.h = h; return cv.u;
}
__device__ __forceinline__ f32x4 zero4() { f32x4 z = {0.f, 0.f, 0.f, 0.f}; return z; }

// async global->LDS, 16B per lane. LDS dest is wave-uniform base + lane*16.
__device__ __forceinline__ void gload_lds16(const u16* g, u16* l) {
  __builtin_amdgcn_global_load_lds(
      (__attribute__((address_space(1))) void*)g,
      (__attribute__((address_space(3))) void*)l, 16, 0, 0);
}

// K-row permutation: sK physical row r holds K logical row LK(r) of the tile.
// Swapped-QK (mfma(K,Q)) output then lands IN-REGISTER in the exact PV
// A-fragment layout (k = 32*ks2 + 8*quad + j), eliminating the P LDS round-trip.
__device__ __forceinline__ int LK(int r) {
  return (r & 0x23) | ((r & 0x0C) << 1) | ((r & 0x10) >> 2);
}

// ---------------- fp32 -> bf16 convert (X) ----------------
__global__ void cvt_f32_bf16(const float* __restrict__ in, u16* __restrict__ out) {
  const size_t i = ((size_t)blockIdx.x * 256 + threadIdx.x) * 8;
  f32x4 a = *(const f32x4*)&in[i];
  f32x4 b = *(const f32x4*)&in[i + 4];
  short8 o;
#pragma unroll
  for (int j = 0; j < 4; ++j) { o[j] = (short)f2b(a[j]); o[4 + j] = (short)f2b(b[j]); }
  *(short8*)&out[i] = o;
}

// ------------- weight transpose + fp32->bf16 convert: [R][C] -> [C][R] -------------
__global__ void transpose_k(const float* __restrict__ in, u16* __restrict__ out,
                            int R, int C) {
  __shared__ u16 tile[32][33];
  const int tx = threadIdx.x, ty = threadIdx.y;
  const int c = blockIdx.x * 32 + tx;
  const int r0 = blockIdx.y * 32;
  for (int i = ty; i < 32; i += 8) tile[i][tx] = f2b(in[(size_t)(r0 + i) * C + c]);
  __syncthreads();
  const int oc = r0 + tx;
  const int c0 = blockIdx.x * 32;
  for (int i = ty; i < 32; i += 8) out[(size_t)(c0 + i) * R + oc] = tile[tx][i];
}

// ------- 256x128 pipelined GEMM, A[M][K] @ Bt[N][K]^T, K=1024, bf16 in -------
// R7: counted-vmcnt software pipeline (T3/T4) replacing the m97 2-barrier
// structure whose vmcnt(0)-drain-per-K-step was the known wall.
// Per K-tile (BK=64): STAGE burst0 (3 gload_lds) -> s_waitcnt vmcnt(3) (tile kt
// guaranteed landed; next-tile loads stay in flight, NEVER drained to 0 until
// the last tile) -> raw s_barrier -> ds_read af(8)+bf01(4) -> lgkmcnt(0)+
// sched_barrier -> 16 MFMA -> STAGE burst1 -> ds_read bf23(4) -> lgkmcnt(0) ->
// 16 MFMA. One barrier + one counted vmcnt per K-tile.
// Safety: tile kt's 6 loads are the only ones older than the newest 6 at the
// kt-top wait -> vmcnt(3)+barrier proves all waves' tile-kt DMA landed.
// Laggard LDS reads are lgkmcnt(0)-drained before their wave reaches the next
// barrier, which precedes any overwrite of that buffer (2-deep dbuf).
// LDS bank swizzle: source slot s^(r&7), read slot kc^(row&7) (rule 21,
// both-sides; same pattern as attn's verified staging).
// 8 waves: wm=w>>1 (4 x 64-row slabs), wn=w&1 (2 x 64-col slabs).
template <int MODE>
__global__ __launch_bounds__(512, 2) void gemm_pipe(
    const u16* __restrict__ A, const u16* __restrict__ Bt,
    const float* __restrict__ bias, u16* __restrict__ o0,
    u16* __restrict__ o1, u16* __restrict__ o2, float* __restrict__ of) {
  __shared__ __align__(16) u16 sA[2][256 * 64];   // 64 KB
  __shared__ __align__(16) u16 sB[2][128 * 64];   // 32 KB

  const int tid = threadIdx.x;
  const int lane = tid & 63;
  const int w = tid >> 6;
  const int quad = lane >> 4, ln = lane & 15;
  const int wm = w >> 1, wn = w & 1;

  const int NT = (MODE == 0) ? 24 : 8;     // N/128
  const int nwg = gridDim.x, cpx = nwg >> 3;
  const int id = blockIdx.x;
  const int swz = (id & 7) * cpx + (id >> 3);   // bijective: nwg % 8 == 0
  const int m0 = (swz / NT) * 256, n0 = (swz % NT) * 128;

  // staging: per thread fixed row r0 = tid>>3 (+slab offsets), slot s0 = tid&7.
  // LDS dest linear (row*64 + s0*8 == tid*8 within slab); source pre-swizzled.
  const int r0 = tid >> 3, s0 = tid & 7;
  const u16* aSrc = A + (size_t)(m0 + r0) * KDIM + (s0 ^ (r0 & 7)) * 8;
  const u16* bSrc = Bt + (size_t)(n0 + r0) * KDIM + (s0 ^ (r0 & 7)) * 8;

  f32x4 acc[4][4];
#pragma unroll
  for (int i = 0; i < 4; ++i)
#pragma unroll
    for (int j = 0; j < 4; ++j) acc[i][j] = zero4();

  // burst p of tile ktn: p0 -> A rows {0,64,128}; p1 -> A row 192 + B rows {0,64}
  auto STAGE = [&](int ktn, int p) {
    u16* dA = &sA[ktn & 1][0];
    u16* dB = &sB[ktn & 1][0];
    const int k0n = ktn * 64;
    if (p == 0) {
      gload_lds16(aSrc + k0n,                        dA + tid * 8);
      gload_lds16(aSrc + (size_t)64 * KDIM + k0n,    dA + 64 * 64 + tid * 8);
      gload_lds16(aSrc + (size_t)128 * KDIM + k0n,   dA + 128 * 64 + tid * 8);
    } else {
      gload_lds16(aSrc + (size_t)192 * KDIM + k0n,   dA + 192 * 64 + tid * 8);
      gload_lds16(bSrc + k0n,                        dB + tid * 8);
      gload_lds16(bSrc + (size_t)64 * KDIM + k0n,    dB + 64 * 64 + tid * 8);
    }
  };

  // prologue: stage tile 0 fully (6 loads in flight)
  STAGE(0, 0);
  STAGE(0, 1);

#pragma unroll 1
  for (int kt = 0; kt < KDIM / 64; ++kt) {
    const int bb = kt & 1;
    const u16* lA = &sA[bb][0];
    const u16* lB = &sB[bb][0];

    if (kt < KDIM / 64 - 1) {
      STAGE(kt + 1, 0);
      asm volatile("s_waitcnt vmcnt(3)" ::: "memory");
    } else {
      asm volatile("s_waitcnt vmcnt(0)" ::: "memory");
    }
    __builtin_amdgcn_s_barrier();
    asm volatile("" ::: "memory");

    short8 af[4][2], bf[2][2];
#pragma unroll
    for (int mf = 0; mf < 4; ++mf)
#pragma unroll
      for (int kk = 0; kk < 2; ++kk)
        af[mf][kk] = *(const short8*)&lA[(wm * 64 + mf * 16 + ln) * 64 +
                                         ((((kk << 2) | quad)) ^ (ln & 7)) * 8];
#pragma unroll
    for (int nf = 0; nf < 2; ++nf)
#pragma unroll
      for (int kk = 0; kk < 2; ++kk)
        bf[nf][kk] = *(const short8*)&lB[(wn * 64 + nf * 16 + ln) * 64 +
                                         ((((kk << 2) | quad)) ^ (ln & 7)) * 8];
    asm volatile("s_waitcnt lgkmcnt(0)" ::: "memory");
    __builtin_amdgcn_sched_barrier(0);
    __builtin_amdgcn_s_setprio(1);
#pragma unroll
    for (int kk = 0; kk < 2; ++kk)
#pragma unroll
      for (int mf = 0; mf < 4; ++mf)
#pragma unroll
        for (int nf = 0; nf < 2; ++nf)
          acc[mf][nf] = __builtin_amdgcn_mfma_f32_16x16x32_bf16(
              af[mf][kk], bf[nf][kk], acc[mf][nf], 0, 0, 0);
    __builtin_amdgcn_s_setprio(0);

    if (kt < KDIM / 64 - 1) STAGE(kt + 1, 1);
#pragma unroll
    for (int nf = 0; nf < 2; ++nf)
#pragma unroll
      for (int kk = 0; kk < 2; ++kk)
        bf[nf][kk] = *(const short8*)&lB[(wn * 64 + (nf + 2) * 16 + ln) * 64 +
                                         ((((kk << 2) | quad)) ^ (ln & 7)) * 8];
    asm volatile("s_waitcnt lgkmcnt(0)" ::: "memory");
    __builtin_amdgcn_sched_barrier(0);
    __builtin_amdgcn_s_setprio(1);
#pragma unroll
    for (int kk = 0; kk < 2; ++kk)
#pragma unroll
      for (int mf = 0; mf < 4; ++mf)
#pragma unroll
        for (int nf = 0; nf < 2; ++nf)
          acc[mf][nf + 2] = __builtin_amdgcn_mfma_f32_16x16x32_bf16(
              af[mf][kk], bf[nf][kk], acc[mf][nf + 2], 0, 0, 0);
    __builtin_amdgcn_s_setprio(0);
  }

  // ---------------- epilogue ----------------
  if (MODE == 0) {
    const int which = n0 >> 10;           // 0=Q 1=K 2=V (128-wide tile never crosses)
    const int h = (n0 & 1023) >> 7;       // head, block-uniform
#pragma unroll
    for (int mf = 0; mf < 4; ++mf) {
      const int rbase = m0 + wm * 64 + mf * 16 + quad * 4;  // 4 consecutive rows
      const int b = rbase >> 11;
      const int n = rbase & 2047;
#pragma unroll
      for (int nf = 0; nf < 4; ++nf) {
        const int dcol = wn * 64 + nf * 16 + ln;            // 0..127
        const float bv = bias[n0 + dcol];
        if (which == 0) {
          u16* p = o0 + ((size_t)(b * NH + h) * NSEQ + n) * HD + dcol;
#pragma unroll
          for (int rr = 0; rr < 4; ++rr)
            p[(size_t)rr * HD] = f2b((acc[mf][nf][rr] + bv) * QSCALE);
        } else if (which == 1) {
          u16* p = o1 + ((size_t)(b * NH + h) * NSEQ + n) * HD + dcol;
#pragma unroll
          for (int rr = 0; rr < 4; ++rr)
            p[(size_t)rr * HD] = f2b(acc[mf][nf][rr] + bv);
        } else {
          u16x4 pk;
#pragma unroll
          for (int rr = 0; rr < 4; ++rr) pk[rr] = f2b(acc[mf][nf][rr] + bv);
          *(u16x4*)&o2[((size_t)(b * NH + h) * HD + dcol) * NSEQ + n] = pk;
        }
      }
    }
  } else {
#pragma unroll
    for (int mf = 0; mf < 4; ++mf) {
      const int rbase = m0 + wm * 64 + mf * 16 + quad * 4;
#pragma unroll
      for (int nf = 0; nf < 4; ++nf) {
        const int col = n0 + wn * 64 + nf * 16 + ln;
        const float bv = bias[col];
#pragma unroll
        for (int rr = 0; rr < 4; ++rr)
          of[(size_t)(rbase + rr) * DMODEL + col] = acc[mf][nf][rr] + bv;
      }
    }
  }
}

// ------------- flash attention: grid (N/128, B*H), 4 waves x 32 q-rows -------------
// R5 verified structure (88.6 us): swapped-QK + LK permute -> P in-register;
// K/V double-buffered via global_load_lds w=16, XOR swizzle both sides;
// SM pipelined one n-chunk behind QK; vf reads interleaved under MFMA clusters.
__global__ __launch_bounds__(256, 2) void attn_fused(
    const u16* __restrict__ Q, const u16* __restrict__ K,
    const u16* __restrict__ Vt, u16* __restrict__ AO) {
  __shared__ __align__(16) u16 sK[2][64 * 128];   // [kv_phys(LK-permuted)][d]
  __shared__ __align__(16) u16 sV[2][128 * 64];   // [d][kv]

  const int tid = threadIdx.x;
  const int w = tid >> 6, lane = tid & 63;
  const int quad = lane >> 4, ln = lane & 15;
  const int bh = blockIdx.y;
  const int q0 = blockIdx.x * 128;

  const u16* Qb = Q + ((size_t)bh * NSEQ + q0) * HD;
  const u16* Kb = K + (size_t)bh * NSEQ * HD;
  const u16* Vb = Vt + (size_t)bh * HD * NSEQ;

  // staging source offsets (u16 units): LDS dest linear, source carries the
  // LK row-permute (K) and the slot^row XOR swizzle (K and V).
  int gk_off[4], gv_off[4];
#pragma unroll
  for (int j = 0; j < 4; ++j) {
    const int c = (w * 4 + j) * 64 + lane;      // 16B-chunk id 0..1023
    const int rk = c >> 4, sk_ = c & 15;        // K: 64 rows x 16 slots
    gk_off[j] = LK(rk) * HD + (sk_ ^ (rk & 7)) * 8;
    const int rv = c >> 3, sv_ = c & 7;         // V: 128 rows x 8 slots
    gv_off[j] = rv * NSEQ + (sv_ ^ (rv & 7)) * 8;
  }

  // loop-invariant LDS read offsets (u16 units)
  int kbase[4], kslot[4], vfo[2][8];
#pragma unroll
  for (int n = 0; n < 4; ++n) kbase[n] = (n * 16 + ln) * 128;
#pragma unroll
  for (int ks = 0; ks < 4; ++ks)
    kslot[ks] = (((ks << 2) | quad) ^ (ln & 7)) * 8;
#pragma unroll
  for (int ks2 = 0; ks2 < 2; ++ks2)
#pragma unroll
    for (int dt = 0; dt < 8; ++dt)
      vfo[ks2][dt] = (dt * 16 + ln) * 64 + ((((ks2 << 2) | quad) ^ (ln & 7)) * 8);

  // Q fragments (B-operand layout) straight from global (one-time)
  short8 qf[2][4];
#pragma unroll
  for (int mt = 0; mt < 2; ++mt)
#pragma unroll
    for (int ks = 0; ks < 4; ++ks)
      qf[mt][ks] = *(const short8*)&Qb[(size_t)(w * 32 + mt * 16 + ln) * HD +
                                       ks * 32 + quad * 8];

  f32x4 o[2][8];
#pragma unroll
  for (int mt = 0; mt < 2; ++mt)
#pragma unroll
    for (int dt = 0; dt < 8; ++dt) o[mt][dt] = zero4();
  float l_part[2] = {0.f, 0.f};

  // stage tile 0 into buffer 0
#pragma unroll
  for (int j = 0; j < 4; ++j) {
    gload_lds16(Kb + gk_off[j], &sK[0][(w * 4 + j) * 512]);
    gload_lds16(Vb + gv_off[j], &sV[0][(w * 4 + j) * 512]);
  }

  union PU { u32x4 u; short8 s; };

#pragma unroll 1
  for (int it = 0; it < NSEQ / 128; ++it) {
#pragma unroll
    for (int c2 = 0; c2 < 2; ++c2) {
      __syncthreads();  // drains vmcnt: buf[c2] ready; buf[c2^1] reads done

      const int kvn = it * 128 + c2 * 64 + 64;
      if (kvn < NSEQ) {   // prefetch next tile into the other buffer
#pragma unroll
        for (int j = 0; j < 4; ++j) {
          gload_lds16(Kb + (size_t)kvn * HD + gk_off[j],
                      &sK[c2 ^ 1][(w * 4 + j) * 512]);
          gload_lds16(Vb + kvn + gv_off[j], &sV[c2 ^ 1][(w * 4 + j) * 512]);
        }
      }
      const u16* skr = &sK[c2][0];
      const u16* svr = &sV[c2][0];

      __builtin_amdgcn_s_setprio(1);

      f32x4 sacc[4][2];   // [n][mt]
      PU ph[2][2];        // [mt][ks2] packed P (PV A-fragment)
      short8 vf0[8], vf1[8];

      // SM chunk for completed n-tile m: exp2 + l-sum + cheap bf16 pair-pack
      auto SM = [&](int m) {
#pragma unroll
        for (int mt = 0; mt < 2; ++mt) {
          float e0 = exp2f(sacc[m][mt][0]);
          float e1 = exp2f(sacc[m][mt][1]);
          float e2 = exp2f(sacc[m][mt][2]);
          float e3 = exp2f(sacc[m][mt][3]);
          l_part[mt] += (e0 + e1) + (e2 + e3);
          unsigned a0 = __float_as_uint(e0) + 0x8000u;
          unsigned a1 = __float_as_uint(e1) + 0x8000u;
          unsigned a2 = __float_as_uint(e2) + 0x8000u;
          unsigned a3 = __float_as_uint(e3) + 0x8000u;
          // dword = hi_bf16[31:16] | lo_bf16[31:16]>>16  (elem order lo,hi)
          ph[mt][m >> 1].u[(m & 1) * 2 + 0] = __builtin_amdgcn_perm(a1, a0, 0x07060302);
          ph[mt][m >> 1].u[(m & 1) * 2 + 1] = __builtin_amdgcn_perm(a3, a2, 0x07060302);
        }
      };

      // QK with SM pipelined one n-chunk behind; vf ks2=0 reads issued under
      // the n=1 / n=2 MFMA clusters (LDS pipe busy while matrix pipe runs).
#pragma unroll
      for (int n = 0; n < 4; ++n) {
#pragma unroll
        for (int mt = 0; mt < 2; ++mt) sacc[n][mt] = zero4();
#pragma unroll
        for (int ks = 0; ks < 4; ++ks) {
          short8 kf = *(const short8*)&skr[kbase[n] + kslot[ks]];
          sacc[n][0] = __builtin_amdgcn_mfma_f32_16x16x32_bf16(
              kf, qf[0][ks], sacc[n][0], 0, 0, 0);
          sacc[n][1] = __builtin_amdgcn_mfma_f32_16x16x32_bf16(
              kf, qf[1][ks], sacc[n][1], 0, 0, 0);
        }
        if (n == 1) {
#pragma unroll
          for (int dt = 0; dt < 4; ++dt)
            vf0[dt] = *(const short8*)&svr[vfo[0][dt]];
        } else if (n == 2) {
#pragma unroll
          for (int dt = 4; dt < 8; ++dt)
            vf0[dt] = *(const short8*)&svr[vfo[0][dt]];
        }
        if (n) SM(n - 1);
      }

      // PV ks2=0 (needs SM(0),SM(1): done)
      {
        short8 pf0 = ph[0][0].s, pf1 = ph[1][0].s;
#pragma unroll
        for (int dt = 0; dt < 8; ++dt) {
          o[0][dt] = __builtin_amdgcn_mfma_f32_16x16x32_bf16(
              pf0, vf0[dt], o[0][dt], 0, 0, 0);
          o[1][dt] = __builtin_amdgcn_mfma_f32_16x16x32_bf16(
              pf1, vf0[dt], o[1][dt], 0, 0, 0);
        }
      }
      // vf ks2=1 reads issue under the tail of PV0 / SM(3) VALU
#pragma unroll
      for (int dt = 0; dt < 8; ++dt)
        vf1[dt] = *(const short8*)&svr[vfo[1][dt]];
      SM(3);   // VALU overlaps PV0 MFMAs above / PV1 below
      // PV ks2=1 (needs SM(2),SM(3): done)
      {
        short8 pf0 = ph[0][1].s, pf1 = ph[1][1].s;
#pragma unroll
        for (int dt = 0; dt < 8; ++dt) {
          o[0][dt] = __builtin_amdgcn_mfma_f32_16x16x32_bf16(
              pf0, vf1[dt], o[0][dt], 0, 0, 0);
          o[1][dt] = __builtin_amdgcn_mfma_f32_16x16x32_bf16(
              pf1, vf1[dt], o[1][dt], 0, 0, 0);
        }
      }
      __builtin_amdgcn_s_setprio(0);
    }
  }

  // epilogue: l_part[mt] holds this lane's partial sum for q = 16mt+ln.
  // Sum across quads, then redistribute to output rows q' = 16mt+4quad+rr.
  const int b = bh >> 3, h = bh & 7;
#pragma unroll
  for (int mt = 0; mt < 2; ++mt) {
    float v = l_part[mt];
    v += __shfl_xor(v, 16, 64);
    v += __shfl_xor(v, 32, 64);
    float inv[4];
#pragma unroll
    for (int rr = 0; rr < 4; ++rr)
      inv[rr] = 1.0f / __shfl(v, quad * 4 + rr, 64);
    const int rbase = q0 + w * 32 + mt * 16 + quad * 4;
#pragma unroll
    for (int dt = 0; dt < 8; ++dt) {
      const int d = dt * 16 + ln;
#pragma unroll
      for (int rr = 0; rr < 4; ++rr)
        AO[((size_t)b * NSEQ + rbase + rr) * DMODEL + h * HD + d] =
            f2b(o[mt][dt][rr] * inv[rr]);
    }
  }
}

extern "C" void kernel_launch(void* const* d_in, const int* in_sizes, int n_in,
                              void* d_out, int out_size, void* d_ws, size_t ws_size,
                              hipStream_t stream) {
  // ALL tensors are FP32 per the reference (jnp.float32 everywhere).
  const float* X = (const float*)d_in[0];      // [4,2048,1024]
  const float* Wqkv = (const float*)d_in[1];   // [1024,3072]
  const float* bqkv = (const float*)d_in[2];   // [3072]
  const float* Wproj = (const float*)d_in[3];  // [1024,1024]
  const float* bproj = (const float*)d_in[4];  // [1024]
  float* out = (float*)d_out;                  // [4,2048,1024] fp32

  // workspace layout (u16 elements): ~92.3 MB total
  const size_t NEED_BYTES =
      2ull * (8388608 /*Xb*/ + 3072 * 1024 + 1024 * 1024 + 3 * 8388608 + 8388608);
  if (ws_size < NEED_BYTES) return;  // signature: absmax == 0.2676 -> ws too small

  u16* ws = (u16*)d_ws;
  u16* Xb = ws;                            // [8192][1024] bf16
  u16* WqkvT = Xb + 8388608;               // [3072][1024] bf16
  u16* WprojT = WqkvT + 3072 * 1024;       // [1024][1024] bf16
  u16* Qb = WprojT + 1024 * 1024;          // [B,H,N,Hd] bf16 (pre-scaled, exp2 dom)
  u16* Kb = Qb + 8388608;                  // [B,H,N,Hd] bf16
  u16* Vtb = Kb + 8388608;                 // [B,H,Hd,N] bf16
  u16* AO = Vtb + 8388608;                 // [B,N,D]   bf16

  cvt_f32_bf16<<<8388608 / (256 * 8), 256, 0, stream>>>(X, Xb);
  transpose_k<<<dim3(3072 / 32, 1024 / 32), dim3(32, 8), 0, stream>>>(Wqkv, WqkvT, 1024, 3072);
  transpose_k<<<dim3(1024 / 32, 1024 / 32), dim3(32, 8), 0, stream>>>(Wproj, WprojT, 1024, 1024);
  gemm_pipe<0><<<768, 512, 0, stream>>>(Xb, WqkvT, bqkv, Qb, Kb, Vtb, nullptr);
  attn_fused<<<dim3(2048 / 128, 32), 256, 0, stream>>>(Qb, Kb, Vtb, AO);
  gemm_pipe<1><<<256, 512, 0, stream>>>(AO, WprojT, bproj, nullptr, nullptr, nullptr, out);
}

// Round 8
// 267.711 us; speedup vs baseline: 1.9499x; 1.0079x over previous
//
#include <hip/hip_runtime.h>
#include <hip/hip_bf16.h>
#include <cstdint>

typedef unsigned short u16;
typedef __attribute__((ext_vector_type(8))) short short8;
typedef __attribute__((ext_vector_type(4))) float f32x4;
typedef __attribute__((ext_vector_type(4))) unsigned short u16x4;
typedef __attribute__((ext_vector_type(4))) unsigned int u32x4;

#define NSEQ 2048
#define DMODEL 1024
#define NH 8
#define HD 128
#define KDIM 1024
// 1/sqrt(128) * log2(e): attention computed in exp2 domain
#define QSCALE (0.08838834764831845f * 1.4426950408889634f)

__device__ __forceinline__ u16 f2b(float f) {
  __hip_bfloat16 h = __float2bfloat16(f);
  union { __hip_bfloat16 h; u16 u; } cv; cv.h = h; return cv.u;
}
__device__ __forceinline__ f32x4 zero4() { f32x4 z = {0.f, 0.f, 0.f, 0.f}; return z; }

// async global->LDS, 16B per lane. LDS dest is wave-uniform base + lane*16.
__device__ __forceinline__ void gload_lds16(const u16* g, u16* l) {
  __builtin_amdgcn_global_load_lds(
      (__attribute__((address_space(1))) void*)g,
      (__attribute__((address_space(3))) void*)l, 16, 0, 0);
}

// K-row permutation: sK physical row r holds K logical row LK(r) of the tile.
// Swapped-QK (mfma(K,Q)) output then lands IN-REGISTER in the exact PV
// A-fragment layout (k = 32*ks2 + 8*quad + j), eliminating the P LDS round-trip.
__device__ __forceinline__ int LK(int r) {
  return (r & 0x23) | ((r & 0x0C) << 1) | ((r & 0x10) >> 2);
}

// ---------------- fp32 -> bf16 convert (X) ----------------
__global__ void cvt_f32_bf16(const float* __restrict__ in, u16* __restrict__ out) {
  const size_t i = ((size_t)blockIdx.x * 256 + threadIdx.x) * 8;
  f32x4 a = *(const f32x4*)&in[i];
  f32x4 b = *(const f32x4*)&in[i + 4];
  short8 o;
#pragma unroll
  for (int j = 0; j < 4; ++j) { o[j] = (short)f2b(a[j]); o[4 + j] = (short)f2b(b[j]); }
  *(short8*)&out[i] = o;
}

// ------------- weight transpose + fp32->bf16 convert: [R][C] -> [C][R] -------------
__global__ void transpose_k(const float* __restrict__ in, u16* __restrict__ out,
                            int R, int C) {
  __shared__ u16 tile[32][33];
  const int tx = threadIdx.x, ty = threadIdx.y;
  const int c = blockIdx.x * 32 + tx;
  const int r0 = blockIdx.y * 32;
  for (int i = ty; i < 32; i += 8) tile[i][tx] = f2b(in[(size_t)(r0 + i) * C + c]);
  __syncthreads();
  const int oc = r0 + tx;
  const int c0 = blockIdx.x * 32;
  for (int i = ty; i < 32; i += 8) out[(size_t)(c0 + i) * R + oc] = tile[tx][i];
}

// ------- 128x128 pipelined GEMM, A[M][K] @ Bt[N][K]^T, K=1024, bf16 in -------
// R8: counted-vmcnt pipeline at 2 blocks/CU (R7 post-mortem: 96KB LDS -> 1
// block/CU left every wait uncovered; also fixes R7's stage-before-barrier
// buffer race). Per K-tile:
//   barrier1                      -> all waves done READING buf[(kt+1)&1]
//   STAGE(kt+1): 8 gload_lds      -> overwrite now safe
//   s_waitcnt vmcnt(8)            -> tile kt's 8 landed; kt+1's stay in flight
//   barrier2                      -> ALL waves' tile-kt DMA landed
//   ds_read 16 frags; lgkmcnt(0); 32 MFMA
// Never vmcnt(0) until the last tile. 64KB LDS -> 2 blocks/CU; the second
// block covers this block's waits. LDS bank swizzle: source slot s^(r&7),
// read slot kc^(row&7) (both-sides, verified in attn since R2).
// 4 waves: wm=(w>>1)*64, wn=(w&1)*64; acc 4x4 of 16x16.
template <int MODE>
__global__ __launch_bounds__(256, 2) void gemm_pipe(
    const u16* __restrict__ A, const u16* __restrict__ Bt,
    const float* __restrict__ bias, u16* __restrict__ o0,
    u16* __restrict__ o1, u16* __restrict__ o2, float* __restrict__ of) {
  __shared__ __align__(16) u16 sA[2][128 * 64];   // 32 KB
  __shared__ __align__(16) u16 sB[2][128 * 64];   // 32 KB

  const int tid = threadIdx.x;
  const int lane = tid & 63;
  const int w = tid >> 6;
  const int quad = lane >> 4, ln = lane & 15;
  const int wm = (w >> 1) * 64, wn = (w & 1) * 64;

  const int NT = (MODE == 0) ? 24 : 8;     // N/128
  const int nwg = gridDim.x, cpx = nwg >> 3;
  const int id = blockIdx.x;
  const int swz = (id & 7) * cpx + (id >> 3);   // bijective: nwg % 8 == 0
  const int m0 = (swz / NT) * 128, n0 = (swz % NT) * 128;

  // staging: chunk c = i*256 + tid -> row r = i*32 + (tid>>3), slot s = tid&7.
  // LDS dest linear (c*8 u16); global source pre-swizzled slot s^(r&7).
  const int rr0 = tid >> 3, ss0 = tid & 7;
  size_t a_off[4], b_off[4];
#pragma unroll
  for (int i = 0; i < 4; ++i) {
    const int r = i * 32 + rr0;
    const int so = (ss0 ^ (r & 7)) * 8;
    a_off[i] = (size_t)(m0 + r) * KDIM + so;
    b_off[i] = (size_t)(n0 + r) * KDIM + so;
  }

  f32x4 acc[4][4];
#pragma unroll
  for (int i = 0; i < 4; ++i)
#pragma unroll
    for (int j = 0; j < 4; ++j) acc[i][j] = zero4();

  auto STAGE = [&](int ktn) {
    u16* dA = &sA[ktn & 1][0];
    u16* dB = &sB[ktn & 1][0];
    const int k0n = ktn * 64;
#pragma unroll
    for (int i = 0; i < 4; ++i) {
      gload_lds16(A + a_off[i] + k0n, dA + i * 2048 + tid * 8);
      gload_lds16(Bt + b_off[i] + k0n, dB + i * 2048 + tid * 8);
    }
  };

  // prologue: tile 0 in flight
  STAGE(0);

#pragma unroll 1
  for (int kt = 0; kt < KDIM / 64; ++kt) {
    const u16* lA = &sA[kt & 1][0];
    const u16* lB = &sB[kt & 1][0];

    __builtin_amdgcn_s_barrier();            // reads of buf[(kt+1)&1] all done
    asm volatile("" ::: "memory");
    if (kt < KDIM / 64 - 1) {
      STAGE(kt + 1);
      asm volatile("s_waitcnt vmcnt(8)" ::: "memory");
    } else {
      asm volatile("s_waitcnt vmcnt(0)" ::: "memory");
    }
    __builtin_amdgcn_s_barrier();            // all waves' tile-kt DMA landed
    asm volatile("" ::: "memory");

    short8 af[4][2], bf[4][2];
#pragma unroll
    for (int mf = 0; mf < 4; ++mf)
#pragma unroll
      for (int kk = 0; kk < 2; ++kk)
        af[mf][kk] = *(const short8*)&lA[(wm + mf * 16 + ln) * 64 +
                                         ((((kk << 2) | quad)) ^ (ln & 7)) * 8];
#pragma unroll
    for (int nf = 0; nf < 4; ++nf)
#pragma unroll
      for (int kk = 0; kk < 2; ++kk)
        bf[nf][kk] = *(const short8*)&lB[(wn + nf * 16 + ln) * 64 +
                                         ((((kk << 2) | quad)) ^ (ln & 7)) * 8];
    asm volatile("s_waitcnt lgkmcnt(0)" ::: "memory");
    __builtin_amdgcn_sched_barrier(0);
    __builtin_amdgcn_s_setprio(1);
#pragma unroll
    for (int kk = 0; kk < 2; ++kk)
#pragma unroll
      for (int mf = 0; mf < 4; ++mf)
#pragma unroll
        for (int nf = 0; nf < 4; ++nf)
          acc[mf][nf] = __builtin_amdgcn_mfma_f32_16x16x32_bf16(
              af[mf][kk], bf[nf][kk], acc[mf][nf], 0, 0, 0);
    __builtin_amdgcn_s_setprio(0);
  }

  // ---------------- epilogue ----------------
  if (MODE == 0) {
    const int which = n0 >> 10;           // 0=Q 1=K 2=V (tile never crosses)
    const int h = (n0 & 1023) >> 7;       // head, block-uniform
#pragma unroll
    for (int mf = 0; mf < 4; ++mf) {
      const int rbase = m0 + wm + mf * 16 + quad * 4;  // 4 consecutive rows
      const int b = rbase >> 11;
      const int n = rbase & 2047;
#pragma unroll
      for (int nf = 0; nf < 4; ++nf) {
        const int dcol = wn + nf * 16 + ln;            // 0..127
        const float bv = bias[n0 + dcol];
        if (which == 0) {
          u16* p = o0 + ((size_t)(b * NH + h) * NSEQ + n) * HD + dcol;
#pragma unroll
          for (int rr = 0; rr < 4; ++rr)
            p[(size_t)rr * HD] = f2b((acc[mf][nf][rr] + bv) * QSCALE);
        } else if (which == 1) {
          u16* p = o1 + ((size_t)(b * NH + h) * NSEQ + n) * HD + dcol;
#pragma unroll
          for (int rr = 0; rr < 4; ++rr)
            p[(size_t)rr * HD] = f2b(acc[mf][nf][rr] + bv);
        } else {
          u16x4 pk;
#pragma unroll
          for (int rr = 0; rr < 4; ++rr) pk[rr] = f2b(acc[mf][nf][rr] + bv);
          *(u16x4*)&o2[((size_t)(b * NH + h) * HD + dcol) * NSEQ + n] = pk;
        }
      }
    }
  } else {
#pragma unroll
    for (int mf = 0; mf < 4; ++mf) {
      const int rbase = m0 + wm + mf * 16 + quad * 4;
#pragma unroll
      for (int nf = 0; nf < 4; ++nf) {
        const int col = n0 + wn + nf * 16 + ln;
        const float bv = bias[col];
#pragma unroll
        for (int rr = 0; rr < 4; ++rr)
          of[(size_t)(rbase + rr) * DMODEL + col] = acc[mf][nf][rr] + bv;
      }
    }
  }
}

// ------------- flash attention: grid (N/128, B*H), 4 waves x 32 q-rows -------------
// R5 verified structure (88.6 us): swapped-QK + LK permute -> P in-register;
// K/V double-buffered via global_load_lds w=16, XOR swizzle both sides;
// SM pipelined one n-chunk behind QK; vf reads interleaved under MFMA clusters.
__global__ __launch_bounds__(256, 2) void attn_fused(
    const u16* __restrict__ Q, const u16* __restrict__ K,
    const u16* __restrict__ Vt, u16* __restrict__ AO) {
  __shared__ __align__(16) u16 sK[2][64 * 128];   // [kv_phys(LK-permuted)][d]
  __shared__ __align__(16) u16 sV[2][128 * 64];   // [d][kv]

  const int tid = threadIdx.x;
  const int w = tid >> 6, lane = tid & 63;
  const int quad = lane >> 4, ln = lane & 15;
  const int bh = blockIdx.y;
  const int q0 = blockIdx.x * 128;

  const u16* Qb = Q + ((size_t)bh * NSEQ + q0) * HD;
  const u16* Kb = K + (size_t)bh * NSEQ * HD;
  const u16* Vb = Vt + (size_t)bh * HD * NSEQ;

  // staging source offsets (u16 units): LDS dest linear, source carries the
  // LK row-permute (K) and the slot^row XOR swizzle (K and V).
  int gk_off[4], gv_off[4];
#pragma unroll
  for (int j = 0; j < 4; ++j) {
    const int c = (w * 4 + j) * 64 + lane;      // 16B-chunk id 0..1023
    const int rk = c >> 4, sk_ = c & 15;        // K: 64 rows x 16 slots
    gk_off[j] = LK(rk) * HD + (sk_ ^ (rk & 7)) * 8;
    const int rv = c >> 3, sv_ = c & 7;         // V: 128 rows x 8 slots
    gv_off[j] = rv * NSEQ + (sv_ ^ (rv & 7)) * 8;
  }

  // loop-invariant LDS read offsets (u16 units)
  int kbase[4], kslot[4], vfo[2][8];
#pragma unroll
  for (int n = 0; n < 4; ++n) kbase[n] = (n * 16 + ln) * 128;
#pragma unroll
  for (int ks = 0; ks < 4; ++ks)
    kslot[ks] = (((ks << 2) | quad) ^ (ln & 7)) * 8;
#pragma unroll
  for (int ks2 = 0; ks2 < 2; ++ks2)
#pragma unroll
    for (int dt = 0; dt < 8; ++dt)
      vfo[ks2][dt] = (dt * 16 + ln) * 64 + ((((ks2 << 2) | quad) ^ (ln & 7)) * 8);

  // Q fragments (B-operand layout) straight from global (one-time)
  short8 qf[2][4];
#pragma unroll
  for (int mt = 0; mt < 2; ++mt)
#pragma unroll
    for (int ks = 0; ks < 4; ++ks)
      qf[mt][ks] = *(const short8*)&Qb[(size_t)(w * 32 + mt * 16 + ln) * HD +
                                       ks * 32 + quad * 8];

  f32x4 o[2][8];
#pragma unroll
  for (int mt = 0; mt < 2; ++mt)
#pragma unroll
    for (int dt = 0; dt < 8; ++dt) o[mt][dt] = zero4();
  float l_part[2] = {0.f, 0.f};

  // stage tile 0 into buffer 0
#pragma unroll
  for (int j = 0; j < 4; ++j) {
    gload_lds16(Kb + gk_off[j], &sK[0][(w * 4 + j) * 512]);
    gload_lds16(Vb + gv_off[j], &sV[0][(w * 4 + j) * 512]);
  }

  union PU { u32x4 u; short8 s; };

#pragma unroll 1
  for (int it = 0; it < NSEQ / 128; ++it) {
#pragma unroll
    for (int c2 = 0; c2 < 2; ++c2) {
      __syncthreads();  // drains vmcnt: buf[c2] ready; buf[c2^1] reads done

      const int kvn = it * 128 + c2 * 64 + 64;
      if (kvn < NSEQ) {   // prefetch next tile into the other buffer
#pragma unroll
        for (int j = 0; j < 4; ++j) {
          gload_lds16(Kb + (size_t)kvn * HD + gk_off[j],
                      &sK[c2 ^ 1][(w * 4 + j) * 512]);
          gload_lds16(Vb + kvn + gv_off[j], &sV[c2 ^ 1][(w * 4 + j) * 512]);
        }
      }
      const u16* skr = &sK[c2][0];
      const u16* svr = &sV[c2][0];

      __builtin_amdgcn_s_setprio(1);

      f32x4 sacc[4][2];   // [n][mt]
      PU ph[2][2];        // [mt][ks2] packed P (PV A-fragment)
      short8 vf0[8], vf1[8];

      // SM chunk for completed n-tile m: exp2 + l-sum + cheap bf16 pair-pack
      auto SM = [&](int m) {
#pragma unroll
        for (int mt = 0; mt < 2; ++mt) {
          float e0 = exp2f(sacc[m][mt][0]);
          float e1 = exp2f(sacc[m][mt][1]);
          float e2 = exp2f(sacc[m][mt][2]);
          float e3 = exp2f(sacc[m][mt][3]);
          l_part[mt] += (e0 + e1) + (e2 + e3);
          unsigned a0 = __float_as_uint(e0) + 0x8000u;
          unsigned a1 = __float_as_uint(e1) + 0x8000u;
          unsigned a2 = __float_as_uint(e2) + 0x8000u;
          unsigned a3 = __float_as_uint(e3) + 0x8000u;
          // dword = hi_bf16[31:16] | lo_bf16[31:16]>>16  (elem order lo,hi)
          ph[mt][m >> 1].u[(m & 1) * 2 + 0] = __builtin_amdgcn_perm(a1, a0, 0x07060302);
          ph[mt][m >> 1].u[(m & 1) * 2 + 1] = __builtin_amdgcn_perm(a3, a2, 0x07060302);
        }
      };

      // QK with SM pipelined one n-chunk behind; vf ks2=0 reads issued under
      // the n=1 / n=2 MFMA clusters (LDS pipe busy while matrix pipe runs).
#pragma unroll
      for (int n = 0; n < 4; ++n) {
#pragma unroll
        for (int mt = 0; mt < 2; ++mt) sacc[n][mt] = zero4();
#pragma unroll
        for (int ks = 0; ks < 4; ++ks) {
          short8 kf = *(const short8*)&skr[kbase[n] + kslot[ks]];
          sacc[n][0] = __builtin_amdgcn_mfma_f32_16x16x32_bf16(
              kf, qf[0][ks], sacc[n][0], 0, 0, 0);
          sacc[n][1] = __builtin_amdgcn_mfma_f32_16x16x32_bf16(
              kf, qf[1][ks], sacc[n][1], 0, 0, 0);
        }
        if (n == 1) {
#pragma unroll
          for (int dt = 0; dt < 4; ++dt)
            vf0[dt] = *(const short8*)&svr[vfo[0][dt]];
        } else if (n == 2) {
#pragma unroll
          for (int dt = 4; dt < 8; ++dt)
            vf0[dt] = *(const short8*)&svr[vfo[0][dt]];
        }
        if (n) SM(n - 1);
      }

      // PV ks2=0 (needs SM(0),SM(1): done)
      {
        short8 pf0 = ph[0][0].s, pf1 = ph[1][0].s;
#pragma unroll
        for (int dt = 0; dt < 8; ++dt) {
          o[0][dt] = __builtin_amdgcn_mfma_f32_16x16x32_bf16(
              pf0, vf0[dt], o[0][dt], 0, 0, 0);
          o[1][dt] = __builtin_amdgcn_mfma_f32_16x16x32_bf16(
              pf1, vf0[dt], o[1][dt], 0, 0, 0);
        }
      }
      // vf ks2=1 reads issue under the tail of PV0 / SM(3) VALU
#pragma unroll
      for (int dt = 0; dt < 8; ++dt)
        vf1[dt] = *(const short8*)&svr[vfo[1][dt]];
      SM(3);   // VALU overlaps PV0 MFMAs above / PV1 below
      // PV ks2=1 (needs SM(2),SM(3): done)
      {
        short8 pf0 = ph[0][1].s, pf1 = ph[1][1].s;
#pragma unroll
        for (int dt = 0; dt < 8; ++dt) {
          o[0][dt] = __builtin_amdgcn_mfma_f32_16x16x32_bf16(
              pf0, vf1[dt], o[0][dt], 0, 0, 0);
          o[1][dt] = __builtin_amdgcn_mfma_f32_16x16x32_bf16(
              pf1, vf1[dt], o[1][dt], 0, 0, 0);
        }
      }
      __builtin_amdgcn_s_setprio(0);
    }
  }

  // epilogue: l_part[mt] holds this lane's partial sum for q = 16mt+ln.
  // Sum across quads, then redistribute to output rows q' = 16mt+4quad+rr.
  const int b = bh >> 3, h = bh & 7;
#pragma unroll
  for (int mt = 0; mt < 2; ++mt) {
    float v = l_part[mt];
    v += __shfl_xor(v, 16, 64);
    v += __shfl_xor(v, 32, 64);
    float inv[4];
#pragma unroll
    for (int rr = 0; rr < 4; ++rr)
      inv[rr] = 1.0f / __shfl(v, quad * 4 + rr, 64);
    const int rbase = q0 + w * 32 + mt * 16 + quad * 4;
#pragma unroll
    for (int dt = 0; dt < 8; ++dt) {
      const int d = dt * 16 + ln;
#pragma unroll
      for (int rr = 0; rr < 4; ++rr)
        AO[((size_t)b * NSEQ + rbase + rr) * DMODEL + h * HD + d] =
            f2b(o[mt][dt][rr] * inv[rr]);
    }
  }
}

extern "C" void kernel_launch(void* const* d_in, const int* in_sizes, int n_in,
                              void* d_out, int out_size, void* d_ws, size_t ws_size,
                              hipStream_t stream) {
  // ALL tensors are FP32 per the reference (jnp.float32 everywhere).
  const float* X = (const float*)d_in[0];      // [4,2048,1024]
  const float* Wqkv = (const float*)d_in[1];   // [1024,3072]
  const float* bqkv = (const float*)d_in[2];   // [3072]
  const float* Wproj = (const float*)d_in[3];  // [1024,1024]
  const float* bproj = (const float*)d_in[4];  // [1024]
  float* out = (float*)d_out;                  // [4,2048,1024] fp32

  // workspace layout (u16 elements): ~92.3 MB total
  const size_t NEED_BYTES =
      2ull * (8388608 /*Xb*/ + 3072 * 1024 + 1024 * 1024 + 3 * 8388608 + 8388608);
  if (ws_size < NEED_BYTES) return;  // signature: absmax == 0.2676 -> ws too small

  u16* ws = (u16*)d_ws;
  u16* Xb = ws;                            // [8192][1024] bf16
  u16* WqkvT = Xb + 8388608;               // [3072][1024] bf16
  u16* WprojT = WqkvT + 3072 * 1024;       // [1024][1024] bf16
  u16* Qb = WprojT + 1024 * 1024;          // [B,H,N,Hd] bf16 (pre-scaled, exp2 dom)
  u16* Kb = Qb + 8388608;                  // [B,H,N,Hd] bf16
  u16* Vtb = Kb + 8388608;                 // [B,H,Hd,N] bf16
  u16* AO = Vtb + 8388608;                 // [B,N,D]   bf16

  cvt_f32_bf16<<<8388608 / (256 * 8), 256, 0, stream>>>(X, Xb);
  transpose_k<<<dim3(3072 / 32, 1024 / 32), dim3(32, 8), 0, stream>>>(Wqkv, WqkvT, 1024, 3072);
  transpose_k<<<dim3(1024 / 32, 1024 / 32), dim3(32, 8), 0, stream>>>(Wproj, WprojT, 1024, 1024);
  gemm_pipe<0><<<1536, 256, 0, stream>>>(Xb, WqkvT, bqkv, Qb, Kb, Vtb, nullptr);
  attn_fused<<<dim3(2048 / 128, 32), 256, 0, stream>>>(Qb, Kb, Vtb, AO);
  gemm_pipe<1><<<512, 256, 0, stream>>>(AO, WprojT, bproj, nullptr, nullptr, nullptr, out);
}